// Round 1
// baseline (619.883 us; speedup 1.0000x reference)
//
#include <hip/hip_runtime.h>

// LogSqrt2Quantizer: out[i] = F[bucket(x[i])], plus out[n] = s_x.
//
// bucket: v = rintf(x*65536)+66 (integer-valued fp32 in [66,65602]);
//   octave e = rawexp(v)-133 in [0,10]; +1 if v > 2^(e_real+0.5), i.e.
//   mantissa_field(v) > floor((sqrt(2)-1)*2^23) = 3474675. Exact for integer v.
// F[idx] = lut[qtab[idx]] * s_x, qtab derived by emulating the reference's
//   float32 y/scale -> round-half-even chain exactly (odd |r| hit exact .5
//   ties in fp32; half-even resolves them):
//   idx 0..10 (r=-6..-16) -> q = {15,14,12,10,9,8,6,4,3,2,0}
//   packed as nibbles: 0x0234689ACEF.

__device__ __forceinline__ unsigned bucket_of(float xx) {
    float v = rintf(xx * 65536.0f) + 66.0f;      // exact: *2^16 is exp shift
    unsigned b = __float_as_uint(v);
    unsigned idx = (b >> 23) - 133u;             // octave 0..10
    idx += (b & 0x7FFFFFu) > 3474675u;           // upper half-octave
    return idx;
}

__global__ __launch_bounds__(256) void logq_map_kernel(
    const float* __restrict__ x,
    const float* __restrict__ s_x,
    const float* __restrict__ lut,
    float* __restrict__ out,
    int n)
{
    __shared__ float sF[11];
    const int t = threadIdx.x;
    if (t < 11) {
        int q = (int)((0x0234689ACEFULL >> (4 * t)) & 0xFULL);
        sF[t] = lut[q] * s_x[0];
    }
    __syncthreads();

    const int i = blockIdx.x * 256 + t;
    const int base = i * 4;

    if (base + 3 < n) {
        const float4 xv = *(const float4*)(x + base);
        float4 ov;
        ov.x = sF[bucket_of(xv.x)];
        ov.y = sF[bucket_of(xv.y)];
        ov.z = sF[bucket_of(xv.z)];
        ov.w = sF[bucket_of(xv.w)];
        *(float4*)(out + base) = ov;
    } else if (base < n) {
        for (int j = base; j < n; ++j) out[j] = sF[bucket_of(x[j])];
    }

    if (i == 0) out[n] = s_x[0];   // second tuple element: s_x passthrough
}

extern "C" void kernel_launch(void* const* d_in, const int* in_sizes, int n_in,
                              void* d_out, int out_size, void* d_ws, size_t ws_size,
                              hipStream_t stream) {
    const float* x   = (const float*)d_in[0];
    const float* s_x = (const float*)d_in[1];
    const float* lut = (const float*)d_in[5];
    float* out = (float*)d_out;
    const int n = in_sizes[0];

    const int n4     = (n + 3) / 4;
    const int blocks = (n4 + 255) / 256;
    logq_map_kernel<<<blocks, 256, 0, stream>>>(x, s_x, lut, out, n);
}